// Round 5
// baseline (815.902 us; speedup 1.0000x reference)
//
#include <hip/hip_runtime.h>
#include <hip/hip_bf16.h>
#include <hip/hip_cooperative_groups.h>
#include <stdint.h>

namespace cg = cooperative_groups;

// Problem constants
#define BQ 128    // batch
#define NJ 512    // input capsules j
#define DD 300    // input dim
#define NC 10     // num_capsule i
#define DC 64     // dim_capsule k
#define MM 640    // NC*DC
#define KP 320    // K padded (mult of 64)
#define RT 5      // routing iterations

typedef __attribute__((ext_vector_type(8))) short short8;
typedef __attribute__((ext_vector_type(4))) float f32x4;

__device__ inline float lo16(uint v) { return __uint_as_float(v << 16); }
__device__ inline float hi16(uint v) { return __uint_as_float(v & 0xffff0000u); }

// ---------------- cast kernels ----------------

__global__ void k_cast_x(const float* __restrict__ x, __hip_bfloat16* __restrict__ xb) {
    int g = blockIdx.x * 256 + threadIdx.x;      // 65536*40 groups
    int row = g / 40, cg2 = g - row * 40;
    const float* src = x + (size_t)row * DD + cg2 * 8;
    float4 a = make_float4(0.f, 0.f, 0.f, 0.f), b4 = a;
    if (cg2 < 37) { a = *(const float4*)src; b4 = *(const float4*)(src + 4); }
    else if (cg2 == 37) { a = *(const float4*)src; }
    union { ushort u[8]; uint4 v; } o;
    float f[8] = {a.x, a.y, a.z, a.w, b4.x, b4.y, b4.z, b4.w};
#pragma unroll
    for (int e = 0; e < 8; ++e) {
        __hip_bfloat16 hh = __float2bfloat16(f[e]);
        o.u[e] = *(ushort*)&hh;
    }
    *(uint4*)(xb + (size_t)row * KP + cg2 * 8) = o.v;
}

__global__ void k_cast_w(const float* __restrict__ w, __hip_bfloat16* __restrict__ wt) {
    int idx = blockIdx.x * 256 + threadIdx.x;
    int m = idx / KP, k = idx - m * KP;
    float v = (k < DD) ? w[(size_t)k * MM + m] : 0.f;
    wt[idx] = __float2bfloat16(v);
}

// ---------------- MFMA GEMM (round-3/4 version, unchanged) ----------------

__global__ __launch_bounds__(256)
void k_gemm(const __hip_bfloat16* __restrict__ A,
            const __hip_bfloat16* __restrict__ Bt,
            __hip_bfloat16* __restrict__ C) {
    __shared__ __align__(16) __hip_bfloat16 As[128 * 64];
    __shared__ __align__(16) __hip_bfloat16 Bs[128 * 64];

    const int L  = blockIdx.x;
    const int n0 = ((L >> 3) % 5) * 128;
    const int m0 = ((L / 40) * 8 + (L & 7)) * 128;
    const int t  = threadIdx.x;
    const int w  = t >> 6, lane = t & 63;
    const int wrow = (w >> 1) * 64, wcol = (w & 1) * 64;
    const int quad = lane >> 4, r = lane & 15;

    f32x4 acc[4][4] = {};

    const int srow = t >> 3;
    const int sl   = (t & 7) ^ (srow & 7);
    const __hip_bfloat16* ag = A  + (size_t)(m0 + srow) * KP + sl * 8;
    const __hip_bfloat16* bg = Bt + (size_t)(n0 + srow) * KP + sl * 8;

    for (int kt = 0; kt < KP / 64; ++kt) {
        __syncthreads();
#pragma unroll
        for (int s = 0; s < 4; ++s) {
            __builtin_amdgcn_global_load_lds(
                (const __attribute__((address_space(1))) void*)(ag + (size_t)s * 32 * KP + kt * 64),
                (__attribute__((address_space(3))) void*)(&As[s * 2048 + t * 8]), 16, 0, 0);
            __builtin_amdgcn_global_load_lds(
                (const __attribute__((address_space(1))) void*)(bg + (size_t)s * 32 * KP + kt * 64),
                (__attribute__((address_space(3))) void*)(&Bs[s * 2048 + t * 8]), 16, 0, 0);
        }
        __syncthreads();

#pragma unroll
        for (int hh = 0; hh < 2; ++hh) {
            short8 af[4], bf[4];
#pragma unroll
            for (int mi = 0; mi < 4; ++mi) {
                int rho = wrow + mi * 16 + r;
                int p = (hh * 4 + quad) ^ (rho & 7);
                af[mi] = *(const short8*)&As[rho * 64 + p * 8];
            }
#pragma unroll
            for (int ni = 0; ni < 4; ++ni) {
                int rho = wcol + ni * 16 + r;
                int p = (hh * 4 + quad) ^ (rho & 7);
                bf[ni] = *(const short8*)&Bs[rho * 64 + p * 8];
            }
#pragma unroll
            for (int mi = 0; mi < 4; ++mi)
#pragma unroll
                for (int ni = 0; ni < 4; ++ni)
                    acc[mi][ni] = __builtin_amdgcn_mfma_f32_16x16x32_bf16(
                        af[mi], bf[ni], acc[mi][ni], 0, 0, 0);
        }
    }

#pragma unroll
    for (int mi = 0; mi < 4; ++mi)
#pragma unroll
        for (int ni = 0; ni < 4; ++ni) {
            int col = n0 + wcol + ni * 16 + r;
#pragma unroll
            for (int p = 0; p < 4; ++p) {
                int row = m0 + wrow + mi * 16 + quad * 4 + p;
                C[(size_t)row * MM + col] = __float2bfloat16(acc[mi][ni][p]);
            }
        }
}

// ---------------- cooperative routing: u resident in registers ----------------
// 256 blocks x 512 threads, 1 block/CU, 8 waves (2/SIMD at <=256 VGPR).
// Block = (b, j-half h): 256 j. Thread (kq=t[2:0], jg=t[7:3], ih=t[8]) owns
// 8 j x 5 i x 8 k = 320 bf16 = 40 uint4 regs, loaded from HBM ONCE.
// Per iteration: bl (in-thread 8k dot + 3-stage kq butterfly) -> softmax (LDS)
// -> po (in-thread j-accumulate + 3-stage jg butterfly) -> pbuf -> grid.sync
// -> squash (redundant per block) -> outl.

__global__ __launch_bounds__(512, 2)
void k_route(const __hip_bfloat16* __restrict__ u, float* __restrict__ pbuf,
             float* __restrict__ out) {
    __shared__ __align__(16) char smem[10240 + 10240 + 2560];
    float* blbuf = (float*)smem;               // [10][256] bl logits
    float* pored = (float*)smem;               // [4][640] overlay (blbuf dead by then)
    float* cbuf  = (float*)(smem + 10240);     // [10][256] softmax c
    float* outl  = (float*)(smem + 20480);     // [640] squashed outputs

    cg::grid_group grid = cg::this_grid();

    const int t  = threadIdx.x, blk = blockIdx.x;
    const int b  = blk >> 1, h = blk & 1;
    const int kq = t & 7, jg = (t >> 3) & 31, ih = t >> 8;
    const int lane = t & 63, w = t >> 6, jgh = (t >> 6) & 3;

    // load this thread's u chunk once: 40 x uint4 (16 B), kq-lanes contiguous 128 B
    const __hip_bfloat16* ub =
        u + (size_t)(b * NJ + h * 256 + jg * 8) * MM + (ih * 5) * 64 + kq * 8;
    uint4 ug[40];
#pragma unroll
    for (int jj = 0; jj < 8; ++jj)
#pragma unroll
        for (int il = 0; il < 5; ++il)
            ug[jj * 5 + il] = *(const uint4*)(ub + (size_t)jj * MM + il * 64);

    for (int it = 0; it < RT; ++it) {
        if (it > 0) {
            // ---- bl phase: bl[j,i] = sum_k out[i,k]*u[j,i,k] ----
            float blp[40];
#pragma unroll
            for (int il = 0; il < 5; ++il) {
                f32x4 o0 = *(const f32x4*)&outl[(ih * 5 + il) * 64 + kq * 8];
                f32x4 o1 = *(const f32x4*)&outl[(ih * 5 + il) * 64 + kq * 8 + 4];
#pragma unroll
                for (int jj = 0; jj < 8; ++jj) {
                    uint4 q = ug[jj * 5 + il];
                    float s = lo16(q.x) * o0.x + hi16(q.x) * o0.y
                            + lo16(q.y) * o0.z + hi16(q.y) * o0.w
                            + lo16(q.z) * o1.x + hi16(q.z) * o1.y
                            + lo16(q.w) * o1.z + hi16(q.w) * o1.w;
                    blp[jj * 5 + il] = s;
                }
            }
#pragma unroll
            for (int st = 1; st <= 4; st <<= 1)
#pragma unroll
                for (int e = 0; e < 40; ++e)
                    blp[e] += __shfl_xor(blp[e], st, 64);   // reduce over kq
            if (kq == 0) {
#pragma unroll
                for (int il = 0; il < 5; ++il) {
                    f32x4 w0 = {blp[0 * 5 + il], blp[1 * 5 + il], blp[2 * 5 + il], blp[3 * 5 + il]};
                    f32x4 w1 = {blp[4 * 5 + il], blp[5 * 5 + il], blp[6 * 5 + il], blp[7 * 5 + il]};
                    *(f32x4*)&blbuf[(ih * 5 + il) * 256 + jg * 8]     = w0;
                    *(f32x4*)&blbuf[(ih * 5 + il) * 256 + jg * 8 + 4] = w1;
                }
            }
            __syncthreads();
            // ---- softmax over i, one thread per j ----
            if (t < 256) {
                float v[10], mx = -1e30f;
#pragma unroll
                for (int i = 0; i < 10; ++i) { v[i] = blbuf[i * 256 + t]; mx = fmaxf(mx, v[i]); }
                float ssum = 0.f;
#pragma unroll
                for (int i = 0; i < 10; ++i) { v[i] = __expf(v[i] - mx); ssum += v[i]; }
                float inv = 1.f / ssum;
#pragma unroll
                for (int i = 0; i < 10; ++i) cbuf[i * 256 + t] = v[i] * inv;
            }
            __syncthreads();
        }

        // ---- po phase: po[i,k] = sum_j c[j,i]*u[j,i,k] ----
        float po[40];
#pragma unroll
        for (int e = 0; e < 40; ++e) po[e] = 0.f;
#pragma unroll
        for (int il = 0; il < 5; ++il) {
            float cj[8];
            if (it == 0) {
#pragma unroll
                for (int jj = 0; jj < 8; ++jj) cj[jj] = 0.1f;   // softmax of zeros
            } else {
                f32x4 c0 = *(const f32x4*)&cbuf[(ih * 5 + il) * 256 + jg * 8];
                f32x4 c1 = *(const f32x4*)&cbuf[(ih * 5 + il) * 256 + jg * 8 + 4];
                cj[0] = c0.x; cj[1] = c0.y; cj[2] = c0.z; cj[3] = c0.w;
                cj[4] = c1.x; cj[5] = c1.y; cj[6] = c1.z; cj[7] = c1.w;
            }
#pragma unroll
            for (int jj = 0; jj < 8; ++jj) {
                uint4 q = ug[jj * 5 + il];
                float c = cj[jj];
                po[il * 8 + 0] += c * lo16(q.x); po[il * 8 + 1] += c * hi16(q.x);
                po[il * 8 + 2] += c * lo16(q.y); po[il * 8 + 3] += c * hi16(q.y);
                po[il * 8 + 4] += c * lo16(q.z); po[il * 8 + 5] += c * hi16(q.z);
                po[il * 8 + 6] += c * lo16(q.w); po[il * 8 + 7] += c * hi16(q.w);
            }
        }
#pragma unroll
        for (int st = 8; st <= 32; st <<= 1)
#pragma unroll
            for (int e = 0; e < 40; ++e)
                po[e] += __shfl_xor(po[e], st, 64);          // reduce over jg low bits
        __syncthreads();                                     // blbuf dead -> pored
        if ((lane & 56) == 0) {                              // lanes 0..7 per wave
#pragma unroll
            for (int il = 0; il < 5; ++il) {
                f32x4 w0 = {po[il * 8 + 0], po[il * 8 + 1], po[il * 8 + 2], po[il * 8 + 3]};
                f32x4 w1 = {po[il * 8 + 4], po[il * 8 + 5], po[il * 8 + 6], po[il * 8 + 7]};
                *(f32x4*)&pored[jgh * 640 + (ih * 5 + il) * 64 + kq * 8]     = w0;
                *(f32x4*)&pored[jgh * 640 + (ih * 5 + il) * 64 + kq * 8 + 4] = w1;
            }
        }
        __syncthreads();
        if (t < 160) {
            f32x4 s0 = *(const f32x4*)&pored[0 * 640 + t * 4];
            f32x4 s1 = *(const f32x4*)&pored[1 * 640 + t * 4];
            f32x4 s2 = *(const f32x4*)&pored[2 * 640 + t * 4];
            f32x4 s3 = *(const f32x4*)&pored[3 * 640 + t * 4];
            f32x4 s; 
            s.x = s0.x + s1.x + s2.x + s3.x; s.y = s0.y + s1.y + s2.y + s3.y;
            s.z = s0.z + s1.z + s2.z + s3.z; s.w = s0.w + s1.w + s2.w + s3.w;
            *(f32x4*)&pbuf[(size_t)((it & 1) * 256 + b * 2 + h) * MM + t * 4] = s;
        }

        grid.sync();                                         // pbuf visible grid-wide

        // ---- squash (each block redundantly for its b): wave w -> capsule i ----
        const float* ps = pbuf + (size_t)((it & 1) * 256 + b * 2) * MM;
#pragma unroll
        for (int rep = 0; rep < 2; ++rep) {
            int i = rep * 8 + w;
            if (rep == 0 || w < 2) {
                float s = ps[i * 64 + lane] + ps[MM + i * 64 + lane];
                float sq = s * s;
#pragma unroll
                for (int m = 32; m >= 1; m >>= 1) sq += __shfl_xor(sq, m, 64);
                float val = s * rsqrtf(sq + 1e-7f);
                if (it < RT - 1) outl[i * 64 + lane] = val;
                else if (h == 0) out[(size_t)b * MM + i * 64 + lane] = val;
            }
        }
        __syncthreads();                                     // outl visible for bl
    }
}

// ---------------- launch ----------------

extern "C" void kernel_launch(void* const* d_in, const int* in_sizes, int n_in,
                              void* d_out, int out_size, void* d_ws, size_t ws_size,
                              hipStream_t stream) {
    const float* x = (const float*)d_in[0];   // [128,512,300]
    const float* W = (const float*)d_in[1];   // [1,300,640]
    float* out = (float*)d_out;               // [128,10,64]

    char* ws = (char*)d_ws;
    size_t o = 0;
    __hip_bfloat16* xb = (__hip_bfloat16*)(ws + o); o += (size_t)BQ * NJ * KP * 2;  // 41.9 MB
    __hip_bfloat16* wt = (__hip_bfloat16*)(ws + o); o += (size_t)MM * KP * 2;       // 0.4 MB
    __hip_bfloat16* u  = (__hip_bfloat16*)(ws + o); o += (size_t)BQ * NJ * MM * 2;  // 83.9 MB
    float* pbuf = (float*)(ws + o); o += (size_t)2 * 256 * MM * 4;                  // 1.3 MB

    k_cast_x<<<(BQ * NJ * 40) / 256, 256, 0, stream>>>(x, xb);
    k_cast_w<<<(MM * KP) / 256, 256, 0, stream>>>(W, wt);
    k_gemm<<<2560, 256, 0, stream>>>(xb, wt, u);

    void* args[] = {(void*)&u, (void*)&pbuf, (void*)&out};
    hipLaunchCooperativeKernel((const void*)k_route, dim3(256), dim3(512),
                               args, 0, stream);
}

// Round 6
// 287.772 us; speedup vs baseline: 2.8352x; 2.8352x over previous
//
#include <hip/hip_runtime.h>
#include <hip/hip_bf16.h>
#include <stdint.h>

// Problem constants
#define BQ 128    // batch
#define NJ 512    // input capsules j
#define DD 300    // input dim
#define NC 10     // num_capsule i
#define DC 64     // dim_capsule k
#define MM 640    // NC*DC
#define KP 320    // K padded (mult of 64)
#define RT 5      // routing iterations

typedef __attribute__((ext_vector_type(8))) short short8;
typedef __attribute__((ext_vector_type(4))) float f32x4;

// ---------------- cast / init kernels ----------------

__global__ void k_cast_x(const float* __restrict__ x, __hip_bfloat16* __restrict__ xb) {
    int g = blockIdx.x * 256 + threadIdx.x;      // 65536*40 groups
    int row = g / 40, cg2 = g - row * 40;
    const float* src = x + (size_t)row * DD + cg2 * 8;
    float4 a = make_float4(0.f, 0.f, 0.f, 0.f), b4 = a;
    if (cg2 < 37) { a = *(const float4*)src; b4 = *(const float4*)(src + 4); }
    else if (cg2 == 37) { a = *(const float4*)src; }
    union { ushort u[8]; uint4 v; } o;
    float f[8] = {a.x, a.y, a.z, a.w, b4.x, b4.y, b4.z, b4.w};
#pragma unroll
    for (int e = 0; e < 8; ++e) {
        __hip_bfloat16 hh = __float2bfloat16(f[e]);
        o.u[e] = *(ushort*)&hh;
    }
    *(uint4*)(xb + (size_t)row * KP + cg2 * 8) = o.v;
}

__global__ void k_cast_w(const float* __restrict__ w, __hip_bfloat16* __restrict__ wt) {
    int idx = blockIdx.x * 256 + threadIdx.x;
    int m = idx / KP, k = idx - m * KP;
    float v = (k < DD) ? w[(size_t)k * MM + m] : 0.f;
    wt[idx] = __float2bfloat16(v);
}

__global__ void k_zero(float4* __restrict__ p) {   // zero su (ws re-poisoned each call)
    p[blockIdx.x * 256 + threadIdx.x] = make_float4(0.f, 0.f, 0.f, 0.f);
}

// ---------------- MFMA GEMM + fused column-sum (pass-0 elimination) ----------------

__global__ __launch_bounds__(256)
void k_gemm(const __hip_bfloat16* __restrict__ A,
            const __hip_bfloat16* __restrict__ Bt,
            __hip_bfloat16* __restrict__ C,
            float* __restrict__ su) {              // su[b][640] = sum_j u[b,j,:]
    __shared__ __align__(16) __hip_bfloat16 As[128 * 64];
    __shared__ __align__(16) __hip_bfloat16 Bs[128 * 64];

    const int L  = blockIdx.x;
    const int n0 = ((L >> 3) % 5) * 128;
    const int m0 = ((L / 40) * 8 + (L & 7)) * 128;
    const int t  = threadIdx.x;
    const int w  = t >> 6, lane = t & 63;
    const int wrow = (w >> 1) * 64, wcol = (w & 1) * 64;
    const int quad = lane >> 4, r = lane & 15;

    f32x4 acc[4][4] = {};

    const int srow = t >> 3;
    const int sl   = (t & 7) ^ (srow & 7);
    const __hip_bfloat16* ag = A  + (size_t)(m0 + srow) * KP + sl * 8;
    const __hip_bfloat16* bg = Bt + (size_t)(n0 + srow) * KP + sl * 8;

    for (int kt = 0; kt < KP / 64; ++kt) {
        __syncthreads();
#pragma unroll
        for (int s = 0; s < 4; ++s) {
            __builtin_amdgcn_global_load_lds(
                (const __attribute__((address_space(1))) void*)(ag + (size_t)s * 32 * KP + kt * 64),
                (__attribute__((address_space(3))) void*)(&As[s * 2048 + t * 8]), 16, 0, 0);
            __builtin_amdgcn_global_load_lds(
                (const __attribute__((address_space(1))) void*)(bg + (size_t)s * 32 * KP + kt * 64),
                (__attribute__((address_space(3))) void*)(&Bs[s * 2048 + t * 8]), 16, 0, 0);
        }
        __syncthreads();

#pragma unroll
        for (int hh = 0; hh < 2; ++hh) {
            short8 af[4], bf[4];
#pragma unroll
            for (int mi = 0; mi < 4; ++mi) {
                int rho = wrow + mi * 16 + r;
                int p = (hh * 4 + quad) ^ (rho & 7);
                af[mi] = *(const short8*)&As[rho * 64 + p * 8];
            }
#pragma unroll
            for (int ni = 0; ni < 4; ++ni) {
                int rho = wcol + ni * 16 + r;
                int p = (hh * 4 + quad) ^ (rho & 7);
                bf[ni] = *(const short8*)&Bs[rho * 64 + p * 8];
            }
#pragma unroll
            for (int mi = 0; mi < 4; ++mi)
#pragma unroll
                for (int ni = 0; ni < 4; ++ni)
                    acc[mi][ni] = __builtin_amdgcn_mfma_f32_16x16x32_bf16(
                        af[mi], bf[ni], acc[mi][ni], 0, 0, 0);
        }
    }

#pragma unroll
    for (int mi = 0; mi < 4; ++mi)
#pragma unroll
        for (int ni = 0; ni < 4; ++ni) {
            int col = n0 + wcol + ni * 16 + r;
#pragma unroll
            for (int p = 0; p < 4; ++p) {
                int row = m0 + wrow + mi * 16 + quad * 4 + p;
                C[(size_t)row * MM + col] = __float2bfloat16(acc[mi][ni][p]);
            }
        }

    // fused column-sum: all 128 rows of this block are within one b (512/128=4).
    // In-reg fold over (mi,p) = 16 rows of this quad-group, butterfly over quad,
    // then 2 atomic contributions per column (wrow 0 / 64 waves).
    float cs[4];
#pragma unroll
    for (int ni = 0; ni < 4; ++ni) {
        float s = 0.f;
#pragma unroll
        for (int mi = 0; mi < 4; ++mi)
#pragma unroll
            for (int p = 0; p < 4; ++p) s += acc[mi][ni][p];
        s += __shfl_xor(s, 16, 64);
        s += __shfl_xor(s, 32, 64);
        cs[ni] = s;
    }
    if (quad == 0) {
        int bb = m0 >> 9;
#pragma unroll
        for (int ni = 0; ni < 4; ++ni)
            atomicAdd(&su[(size_t)bb * MM + n0 + wcol + ni * 16 + r], cs[ni]);
    }
}

// ---------------- fused routing pass (round-4 base + outl reg-hoist) ----------------
// Block = (b, quarter q). 512 threads, 8 tiles of TJ=16 j, register->LDS pipelined
// staging. Prologue: squash prev iteration (from su if first, else 4 pbuf quarters).
// out-slice hoisted to 20 VGPRs once per pass (removes 10 ds_read_b64 per tile).

#define TJ 16
#define NT 8
#define TILE_BYTES (TJ * MM * 2)   // 20480

__global__ __launch_bounds__(512)
void k_pass(const __hip_bfloat16* __restrict__ u, const float* __restrict__ pprev,
            float* __restrict__ pnext, int first) {
    // smem: ub 20480 | red 32*161*4=20608 | blj 640 | outl 2560   (44288 B)
    __shared__ __align__(16) char smem[TILE_BYTES + 32 * 161 * 4 + 160 * 4 + MM * 4];
    ushort* ub    = (ushort*)smem;                          // [16][640] bf16 tile
    float*  red   = (float*)(smem + TILE_BYTES);            // [32][161] padded
    float*  blj   = (float*)(smem + TILE_BYTES + 20608);    // [160] = [jd][i]
    float*  outl  = (float*)(smem + TILE_BYTES + 20608 + 640); // [640] out_prev
    float*  pored = (float*)smem;                           // epilogue reuse

    const int t   = threadIdx.x;
    const int blk = blockIdx.x;
    const int b   = blk >> 2, q = blk & 3;
    const int w   = t >> 6, lane = t & 63;
    const int jd  = t >> 5, kg = t & 31;

    const char* ubase = (const char*)(u + (size_t)(b * NJ + q * 128) * MM);

    // preload tile 0 (in flight during prologue)
    uint4 sa = *(const uint4*)(ubase + t * 16);
    uint4 sb = *(const uint4*)(ubase + 8192 + t * 16);
    uint2 sc = *(const uint2*)(ubase + 16384 + t * 8);

    // prologue: outl = squash(out_prev); waves 0..4, two i each
    if (w < 5) {
        float s0, s1;
        if (first) {                                 // out_0 from GEMM colsum
            s0 = 0.1f * pprev[(size_t)b * MM + w * 64 + lane];
            s1 = 0.1f * pprev[(size_t)b * MM + 320 + w * 64 + lane];
        } else {                                     // sum 4 quarter-partials
            const float* pp = pprev + (size_t)b * 4 * MM;
            s0 = 0.f; s1 = 0.f;
#pragma unroll
            for (int qq = 0; qq < 4; ++qq) {
                s0 += pp[qq * MM + w * 64 + lane];
                s1 += pp[qq * MM + 320 + w * 64 + lane];
            }
        }
        float q0 = s0 * s0, q1 = s1 * s1;
#pragma unroll
        for (int m = 32; m >= 1; m >>= 1) {
            q0 += __shfl_xor(q0, m, 64);
            q1 += __shfl_xor(q1, m, 64);
        }
        outl[w * 64 + lane]       = s0 * rsqrtf(q0 + 1e-7f);
        outl[320 + w * 64 + lane] = s1 * rsqrtf(q1 + 1e-7f);
    }
    __syncthreads();                                 // outl visible

    // hoist this thread's out-slice: out[i][kg*2 .. +2], tile-invariant
    float2 oreg[10];
#pragma unroll
    for (int i = 0; i < 10; ++i)
        oreg[i] = *(const float2*)&outl[i * 64 + kg * 2];

    float po[20];
#pragma unroll
    for (int e = 0; e < 20; ++e) po[e] = 0.f;

    for (int tt = 0; tt < NT; ++tt) {
        uint4 na, nb; uint2 nc2;
        if (tt + 1 < NT) {                        // next tile's loads in flight
            const char* ns = ubase + (size_t)(tt + 1) * TILE_BYTES;
            na  = *(const uint4*)(ns + t * 16);
            nb  = *(const uint4*)(ns + 8192 + t * 16);
            nc2 = *(const uint2*)(ns + 16384 + t * 8);
        }
        __syncthreads();                          // prev tile compute done
        *(uint4*)((char*)ub + t * 16)        = sa;
        *(uint4*)((char*)ub + 8192 + t * 16) = sb;
        *(uint2*)((char*)ub + 16384 + t * 8) = sc;
        __syncthreads();                          // tile visible

        const ushort* urow = ub + jd * MM;
        uint uv[10];
#pragma unroll
        for (int i = 0; i < 10; ++i)
            uv[i] = *(const uint*)(urow + i * 64 + kg * 2);   // 2-way alias, free

        // bl partial: dot with hoisted oreg (no LDS)
#pragma unroll
        for (int i = 0; i < 10; ++i) {
            float u0 = __uint_as_float(uv[i] << 16);
            float u1 = __uint_as_float(uv[i] & 0xffff0000u);
            red[kg * 161 + jd * 10 + i] = u0 * oreg[i].x + u1 * oreg[i].y;
        }
        __syncthreads();
        if (t < 160) {                            // t = jd*10 + i
            float s = 0.f;
#pragma unroll
            for (int g = 0; g < 32; ++g) s += red[g * 161 + t];
            blj[t] = s;
        }
        __syncthreads();
        float c[10];
        {
            float bl[10], mx = -1e30f;
#pragma unroll
            for (int i = 0; i < 10; ++i) { bl[i] = blj[jd * 10 + i]; mx = fmaxf(mx, bl[i]); }
            float ssum = 0.f;
#pragma unroll
            for (int i = 0; i < 10; ++i) { bl[i] = __expf(bl[i] - mx); ssum += bl[i]; }
            float inv = 1.f / ssum;
#pragma unroll
            for (int i = 0; i < 10; ++i) c[i] = bl[i] * inv;
        }
#pragma unroll
        for (int i = 0; i < 10; ++i) {
            float u0 = __uint_as_float(uv[i] << 16);
            float u1 = __uint_as_float(uv[i] & 0xffff0000u);
            po[i * 2 + 0] += c[i] * u0;
            po[i * 2 + 1] += c[i] * u1;
        }
        sa = na; sb = nb; sc = nc2;
    }

    // epilogue: fold jd-halves in-register, then LDS transpose over 8 waves
#pragma unroll
    for (int e = 0; e < 20; ++e) po[e] += __shfl_xor(po[e], 32, 64);
    __syncthreads();                              // ub dead -> pored
    if ((t & 63) < 32) {
#pragma unroll
        for (int e = 0; e < 20; ++e) pored[(w * 32 + kg) * 20 + e] = po[e];
    }
    __syncthreads();
    for (int m = t; m < MM; m += 512) {
        int i = m >> 6, k = m & 63, kg2 = k >> 1, kd = k & 1;
        float s = 0.f;
#pragma unroll
        for (int ww = 0; ww < 8; ++ww) s += pored[(ww * 32 + kg2) * 20 + i * 2 + kd];
        pnext[(size_t)blk * MM + m] = s;
    }
}

// final squash: sum the 4 per-quarter partials, normalize each (b,i) 64-vector
__global__ __launch_bounds__(640)
void k_squash(const float* __restrict__ pbuf, float* __restrict__ dst) {
    int b = blockIdx.x, t = threadIdx.x;     // t = i*64 + k; wave = i
    float s = 0.f;
#pragma unroll
    for (int qq = 0; qq < 4; ++qq) s += pbuf[(size_t)(b * 4 + qq) * MM + t];
    float sq = s * s;
#pragma unroll
    for (int m = 32; m >= 1; m >>= 1) sq += __shfl_xor(sq, m, 64);
    dst[(size_t)b * MM + t] = s * rsqrtf(sq + 1e-7f);
}

// ---------------- launch ----------------

extern "C" void kernel_launch(void* const* d_in, const int* in_sizes, int n_in,
                              void* d_out, int out_size, void* d_ws, size_t ws_size,
                              hipStream_t stream) {
    const float* x = (const float*)d_in[0];   // [128,512,300]
    const float* W = (const float*)d_in[1];   // [1,300,640]
    float* out = (float*)d_out;               // [128,10,64]

    char* ws = (char*)d_ws;
    size_t o = 0;
    __hip_bfloat16* xb = (__hip_bfloat16*)(ws + o); o += (size_t)BQ * NJ * KP * 2;  // 41.9 MB
    __hip_bfloat16* wt = (__hip_bfloat16*)(ws + o); o += (size_t)MM * KP * 2;       // 0.4 MB
    __hip_bfloat16* u  = (__hip_bfloat16*)(ws + o); o += (size_t)BQ * NJ * MM * 2;  // 83.9 MB
    float* pb0 = (float*)(ws + o); o += (size_t)512 * MM * 4;                       // 1.3 MB
    float* pb1 = (float*)(ws + o); o += (size_t)512 * MM * 4;                       // 1.3 MB
    float* su  = (float*)(ws + o); o += (size_t)BQ * MM * 4;                        // 0.33 MB

    k_cast_x<<<(BQ * NJ * 40) / 256, 256, 0, stream>>>(x, xb);
    k_cast_w<<<(MM * KP) / 256, 256, 0, stream>>>(W, wt);
    k_zero<<<(BQ * MM) / (4 * 256), 256, 0, stream>>>((float4*)su);
    k_gemm<<<2560, 256, 0, stream>>>(xb, wt, u, su);

    // iterations 1..4 (iteration 0 folded into the GEMM colsum)
    k_pass<<<512, 512, 0, stream>>>(u, su,  pb0, 1);
    k_pass<<<512, 512, 0, stream>>>(u, pb0, pb1, 0);
    k_pass<<<512, 512, 0, stream>>>(u, pb1, pb0, 0);
    k_pass<<<512, 512, 0, stream>>>(u, pb0, pb1, 0);
    k_squash<<<BQ, 640, 0, stream>>>(pb1, out);
}

// Round 7
// 235.031 us; speedup vs baseline: 3.4715x; 1.2244x over previous
//
#include <hip/hip_runtime.h>
#include <hip/hip_bf16.h>
#include <stdint.h>

// Problem constants
#define BQ 128    // batch
#define NJ 512    // input capsules j
#define DD 300    // input dim
#define NC 10     // num_capsule i
#define DC 64     // dim_capsule k
#define MM 640    // NC*DC
#define KP 320    // K padded (mult of 64)
#define RT 5      // routing iterations

typedef __attribute__((ext_vector_type(8))) short short8;
typedef __attribute__((ext_vector_type(4))) float f32x4;

// ---------------- cast / init kernels ----------------

__global__ void k_cast_x(const float* __restrict__ x, __hip_bfloat16* __restrict__ xb) {
    int g = blockIdx.x * 256 + threadIdx.x;      // 65536*40 groups
    int row = g / 40, cg2 = g - row * 40;
    const float* src = x + (size_t)row * DD + cg2 * 8;
    float4 a = make_float4(0.f, 0.f, 0.f, 0.f), b4 = a;
    if (cg2 < 37) { a = *(const float4*)src; b4 = *(const float4*)(src + 4); }
    else if (cg2 == 37) { a = *(const float4*)src; }
    union { ushort u[8]; uint4 v; } o;
    float f[8] = {a.x, a.y, a.z, a.w, b4.x, b4.y, b4.z, b4.w};
#pragma unroll
    for (int e = 0; e < 8; ++e) {
        __hip_bfloat16 hh = __float2bfloat16(f[e]);
        o.u[e] = *(ushort*)&hh;
    }
    *(uint4*)(xb + (size_t)row * KP + cg2 * 8) = o.v;
}

__global__ void k_cast_w(const float* __restrict__ w, __hip_bfloat16* __restrict__ wt) {
    int idx = blockIdx.x * 256 + threadIdx.x;
    int m = idx / KP, k = idx - m * KP;
    float v = (k < DD) ? w[(size_t)k * MM + m] : 0.f;
    wt[idx] = __float2bfloat16(v);
}

__global__ void k_zero(float4* __restrict__ p) {   // zero su (ws re-poisoned each call)
    p[blockIdx.x * 256 + threadIdx.x] = make_float4(0.f, 0.f, 0.f, 0.f);
}

// ---------------- MFMA GEMM + fused column-sum (pass-0 elimination) ----------------

__global__ __launch_bounds__(256)
void k_gemm(const __hip_bfloat16* __restrict__ A,
            const __hip_bfloat16* __restrict__ Bt,
            __hip_bfloat16* __restrict__ C,
            float* __restrict__ su) {              // su[b][640] = sum_j u[b,j,:]
    __shared__ __align__(16) __hip_bfloat16 As[128 * 64];
    __shared__ __align__(16) __hip_bfloat16 Bs[128 * 64];

    const int L  = blockIdx.x;
    const int n0 = ((L >> 3) % 5) * 128;
    const int m0 = ((L / 40) * 8 + (L & 7)) * 128;
    const int t  = threadIdx.x;
    const int w  = t >> 6, lane = t & 63;
    const int wrow = (w >> 1) * 64, wcol = (w & 1) * 64;
    const int quad = lane >> 4, r = lane & 15;

    f32x4 acc[4][4] = {};

    const int srow = t >> 3;
    const int sl   = (t & 7) ^ (srow & 7);
    const __hip_bfloat16* ag = A  + (size_t)(m0 + srow) * KP + sl * 8;
    const __hip_bfloat16* bg = Bt + (size_t)(n0 + srow) * KP + sl * 8;

    for (int kt = 0; kt < KP / 64; ++kt) {
        __syncthreads();
#pragma unroll
        for (int s = 0; s < 4; ++s) {
            __builtin_amdgcn_global_load_lds(
                (const __attribute__((address_space(1))) void*)(ag + (size_t)s * 32 * KP + kt * 64),
                (__attribute__((address_space(3))) void*)(&As[s * 2048 + t * 8]), 16, 0, 0);
            __builtin_amdgcn_global_load_lds(
                (const __attribute__((address_space(1))) void*)(bg + (size_t)s * 32 * KP + kt * 64),
                (__attribute__((address_space(3))) void*)(&Bs[s * 2048 + t * 8]), 16, 0, 0);
        }
        __syncthreads();

#pragma unroll
        for (int hh = 0; hh < 2; ++hh) {
            short8 af[4], bf[4];
#pragma unroll
            for (int mi = 0; mi < 4; ++mi) {
                int rho = wrow + mi * 16 + r;
                int p = (hh * 4 + quad) ^ (rho & 7);
                af[mi] = *(const short8*)&As[rho * 64 + p * 8];
            }
#pragma unroll
            for (int ni = 0; ni < 4; ++ni) {
                int rho = wcol + ni * 16 + r;
                int p = (hh * 4 + quad) ^ (rho & 7);
                bf[ni] = *(const short8*)&Bs[rho * 64 + p * 8];
            }
#pragma unroll
            for (int mi = 0; mi < 4; ++mi)
#pragma unroll
                for (int ni = 0; ni < 4; ++ni)
                    acc[mi][ni] = __builtin_amdgcn_mfma_f32_16x16x32_bf16(
                        af[mi], bf[ni], acc[mi][ni], 0, 0, 0);
        }
    }

#pragma unroll
    for (int mi = 0; mi < 4; ++mi)
#pragma unroll
        for (int ni = 0; ni < 4; ++ni) {
            int col = n0 + wcol + ni * 16 + r;
#pragma unroll
            for (int p = 0; p < 4; ++p) {
                int row = m0 + wrow + mi * 16 + quad * 4 + p;
                C[(size_t)row * MM + col] = __float2bfloat16(acc[mi][ni][p]);
            }
        }

    // fused column-sum: 128 rows of this block lie within one b (512 rows/b).
    // In-reg fold over (mi,p)=16 rows, butterfly over quad (x4), one atomic per
    // (wave, ni, r): 2 waves contribute per column.
    float cs[4];
#pragma unroll
    for (int ni = 0; ni < 4; ++ni) {
        float s = 0.f;
#pragma unroll
        for (int mi = 0; mi < 4; ++mi)
#pragma unroll
            for (int p = 0; p < 4; ++p) s += acc[mi][ni][p];
        s += __shfl_xor(s, 16, 64);
        s += __shfl_xor(s, 32, 64);
        cs[ni] = s;
    }
    if (quad == 0) {
        int bb = m0 >> 9;
#pragma unroll
        for (int ni = 0; ni < 4; ++ni)
            atomicAdd(&su[(size_t)bb * MM + n0 + wcol + ni * 16 + r], cs[ni]);
    }
}

// ---------------- fused routing pass (EXACT round-4 inner loop; no oreg hoist) ----------------
// Block = (b, quarter q). 512 threads, 8 tiles of TJ=16 j, register->LDS pipelined
// staging. Prologue: squash prev iteration (from su if first, else 4 pbuf quarters).

#define TJ 16
#define NT 8
#define TILE_BYTES (TJ * MM * 2)   // 20480

__global__ __launch_bounds__(512)
void k_pass(const __hip_bfloat16* __restrict__ u, const float* __restrict__ pprev,
            float* __restrict__ pnext, int first) {
    // smem: ub 20480 | red 32*161*4=20608 | blj 640 | outl 2560   (44288 B)
    __shared__ __align__(16) char smem[TILE_BYTES + 32 * 161 * 4 + 160 * 4 + MM * 4];
    ushort* ub    = (ushort*)smem;                          // [16][640] bf16 tile
    float*  red   = (float*)(smem + TILE_BYTES);            // [32][161] padded
    float*  blj   = (float*)(smem + TILE_BYTES + 20608);    // [160] = [jd][i]
    float*  outl  = (float*)(smem + TILE_BYTES + 20608 + 640); // [640] out_prev
    float*  pored = (float*)smem;                           // epilogue reuse

    const int t   = threadIdx.x;
    const int blk = blockIdx.x;
    const int b   = blk >> 2, q = blk & 3;
    const int w   = t >> 6, lane = t & 63;
    const int jd  = t >> 5, kg = t & 31;

    const char* ubase = (const char*)(u + (size_t)(b * NJ + q * 128) * MM);

    // preload tile 0 (in flight during prologue)
    uint4 sa = *(const uint4*)(ubase + t * 16);
    uint4 sb = *(const uint4*)(ubase + 8192 + t * 16);
    uint2 sc = *(const uint2*)(ubase + 16384 + t * 8);

    // prologue: outl = squash(out_prev); waves 0..4, two i each
    if (w < 5) {
        float s0, s1;
        if (first) {                                 // out_0 from GEMM colsum
            s0 = 0.1f * pprev[(size_t)b * MM + w * 64 + lane];
            s1 = 0.1f * pprev[(size_t)b * MM + 320 + w * 64 + lane];
        } else {                                     // sum 4 quarter-partials
            const float* pp = pprev + (size_t)b * 4 * MM;
            s0 = 0.f; s1 = 0.f;
#pragma unroll
            for (int qq = 0; qq < 4; ++qq) {
                s0 += pp[qq * MM + w * 64 + lane];
                s1 += pp[qq * MM + 320 + w * 64 + lane];
            }
        }
        float q0 = s0 * s0, q1 = s1 * s1;
#pragma unroll
        for (int m = 32; m >= 1; m >>= 1) {
            q0 += __shfl_xor(q0, m, 64);
            q1 += __shfl_xor(q1, m, 64);
        }
        outl[w * 64 + lane]       = s0 * rsqrtf(q0 + 1e-7f);
        outl[320 + w * 64 + lane] = s1 * rsqrtf(q1 + 1e-7f);
    }

    float po[20];
#pragma unroll
    for (int e = 0; e < 20; ++e) po[e] = 0.f;

    for (int tt = 0; tt < NT; ++tt) {
        uint4 na, nb; uint2 nc2;
        if (tt + 1 < NT) {                        // next tile's loads in flight
            const char* ns = ubase + (size_t)(tt + 1) * TILE_BYTES;
            na  = *(const uint4*)(ns + t * 16);
            nb  = *(const uint4*)(ns + 8192 + t * 16);
            nc2 = *(const uint2*)(ns + 16384 + t * 8);
        }
        __syncthreads();                          // prev tile compute done (outl visible too)
        *(uint4*)((char*)ub + t * 16)        = sa;
        *(uint4*)((char*)ub + 8192 + t * 16) = sb;
        *(uint2*)((char*)ub + 16384 + t * 8) = sc;
        __syncthreads();                          // tile visible

        const ushort* urow = ub + jd * MM;
        uint uv[10];
#pragma unroll
        for (int i = 0; i < 10; ++i)
            uv[i] = *(const uint*)(urow + i * 64 + kg * 2);   // 2-way alias, free

        // bl partial: dot with outl from LDS (round-4 scheme)
#pragma unroll
        for (int i = 0; i < 10; ++i) {
            float u0 = __uint_as_float(uv[i] << 16);
            float u1 = __uint_as_float(uv[i] & 0xffff0000u);
            float2 oo = *(const float2*)(outl + i * 64 + kg * 2);
            red[kg * 161 + jd * 10 + i] = u0 * oo.x + u1 * oo.y;
        }
        __syncthreads();
        if (t < 160) {                            // t = jd*10 + i
            float s = 0.f;
#pragma unroll
            for (int g = 0; g < 32; ++g) s += red[g * 161 + t];
            blj[t] = s;
        }
        __syncthreads();
        float c[10];
        {
            float bl[10], mx = -1e30f;
#pragma unroll
            for (int i = 0; i < 10; ++i) { bl[i] = blj[jd * 10 + i]; mx = fmaxf(mx, bl[i]); }
            float ssum = 0.f;
#pragma unroll
            for (int i = 0; i < 10; ++i) { bl[i] = __expf(bl[i] - mx); ssum += bl[i]; }
            float inv = 1.f / ssum;
#pragma unroll
            for (int i = 0; i < 10; ++i) c[i] = bl[i] * inv;
        }
#pragma unroll
        for (int i = 0; i < 10; ++i) {
            float u0 = __uint_as_float(uv[i] << 16);
            float u1 = __uint_as_float(uv[i] & 0xffff0000u);
            po[i * 2 + 0] += c[i] * u0;
            po[i * 2 + 1] += c[i] * u1;
        }
        sa = na; sb = nb; sc = nc2;
    }

    // epilogue: fold jd-halves in-register, then LDS transpose over 8 waves
#pragma unroll
    for (int e = 0; e < 20; ++e) po[e] += __shfl_xor(po[e], 32, 64);
    __syncthreads();                              // ub dead -> pored
    if ((t & 63) < 32) {
#pragma unroll
        for (int e = 0; e < 20; ++e) pored[(w * 32 + kg) * 20 + e] = po[e];
    }
    __syncthreads();
    for (int m = t; m < MM; m += 512) {
        int i = m >> 6, k = m & 63, kg2 = k >> 1, kd = k & 1;
        float s = 0.f;
#pragma unroll
        for (int ww = 0; ww < 8; ++ww) s += pored[(ww * 32 + kg2) * 20 + i * 2 + kd];
        pnext[(size_t)blk * MM + m] = s;
    }
}

// final squash: sum the 4 per-quarter partials, normalize each (b,i) 64-vector
__global__ __launch_bounds__(640)
void k_squash(const float* __restrict__ pbuf, float* __restrict__ dst) {
    int b = blockIdx.x, t = threadIdx.x;     // t = i*64 + k; wave = i
    float s = 0.f;
#pragma unroll
    for (int qq = 0; qq < 4; ++qq) s += pbuf[(size_t)(b * 4 + qq) * MM + t];
    float sq = s * s;
#pragma unroll
    for (int m = 32; m >= 1; m >>= 1) sq += __shfl_xor(sq, m, 64);
    dst[(size_t)b * MM + t] = s * rsqrtf(sq + 1e-7f);
}

// ---------------- launch ----------------

extern "C" void kernel_launch(void* const* d_in, const int* in_sizes, int n_in,
                              void* d_out, int out_size, void* d_ws, size_t ws_size,
                              hipStream_t stream) {
    const float* x = (const float*)d_in[0];   // [128,512,300]
    const float* W = (const float*)d_in[1];   // [1,300,640]
    float* out = (float*)d_out;               // [128,10,64]

    char* ws = (char*)d_ws;
    size_t o = 0;
    __hip_bfloat16* xb = (__hip_bfloat16*)(ws + o); o += (size_t)BQ * NJ * KP * 2;  // 41.9 MB
    __hip_bfloat16* wt = (__hip_bfloat16*)(ws + o); o += (size_t)MM * KP * 2;       // 0.4 MB
    __hip_bfloat16* u  = (__hip_bfloat16*)(ws + o); o += (size_t)BQ * NJ * MM * 2;  // 83.9 MB
    float* pb0 = (float*)(ws + o); o += (size_t)512 * MM * 4;                       // 1.3 MB
    float* pb1 = (float*)(ws + o); o += (size_t)512 * MM * 4;                       // 1.3 MB
    float* su  = (float*)(ws + o); o += (size_t)BQ * MM * 4;                        // 0.33 MB

    k_cast_x<<<(BQ * NJ * 40) / 256, 256, 0, stream>>>(x, xb);
    k_cast_w<<<(MM * KP) / 256, 256, 0, stream>>>(W, wt);
    k_zero<<<(BQ * MM) / (4 * 256), 256, 0, stream>>>((float4*)su);
    k_gemm<<<2560, 256, 0, stream>>>(xb, wt, u, su);

    // iterations 1..4 (iteration 0 folded into the GEMM colsum)
    k_pass<<<512, 512, 0, stream>>>(u, su,  pb0, 1);
    k_pass<<<512, 512, 0, stream>>>(u, pb0, pb1, 0);
    k_pass<<<512, 512, 0, stream>>>(u, pb1, pb0, 0);
    k_pass<<<512, 512, 0, stream>>>(u, pb0, pb1, 0);
    k_squash<<<BQ, 640, 0, stream>>>(pb1, out);
}